// Round 3
// baseline (699.220 us; speedup 1.0000x reference)
//
#include <hip/hip_runtime.h>
#include <hip/hip_bf16.h>
#include <math.h>

// SNN forward, fused per batch element. ALL inputs are FLOAT32; output is
// FLOAT32 [2048][200] (round-2 evidence: writing bf16 left the second half of
// d_out zero and reproduced the stub absmax exactly).
// Pre-pass: convert weights f32->bf16 into d_ws. Main kernel: grid=2048
// (one block per batch row), 256 threads (4 waves), phases L1 -> L2/L3/L4 ->
// OUT+softmax-acc. Spike matrix S[t][n] lives in LDS bf16, updated in place.

#define T_N 150
#define DIN 20
#define H 256
#define NOUT 200
#define TP 160      // padded time rows (10 M-tiles of 16)
#define NMT 10
#define AP 264      // A (spike) row stride, bf16 elems
#define SCS 262     // scan buffer row stride, f32
#define XAP 40      // x staging row stride, bf16 elems

// bf16 weight offsets inside d_ws (elements)
#define WS_W1 0
#define WS_W2 5120
#define WS_W3 70656
#define WS_W4 136192
#define WS_WO 201728
#define WS_TOT 252928

typedef short s16x8 __attribute__((ext_vector_type(8)));
typedef float f32x4 __attribute__((ext_vector_type(4)));

__device__ __forceinline__ unsigned short f2bf(float f) {
  union { float f; unsigned int i; } v; v.f = f;
  unsigned int r = v.i + 0x7FFFu + ((v.i >> 16) & 1u);
  return (unsigned short)(r >> 16);
}

__global__ void cvt_weights(const float* __restrict__ W1, const float* __restrict__ W2,
                            const float* __restrict__ W3, const float* __restrict__ W4,
                            const float* __restrict__ Wo, unsigned short* __restrict__ ws) {
  int idx = blockIdx.x * blockDim.x + threadIdx.x;
  int stride = gridDim.x * blockDim.x;
  for (int i = idx; i < WS_TOT; i += stride) {
    float v;
    if (i < WS_W2)      v = W1[i - WS_W1];
    else if (i < WS_W3) v = W2[i - WS_W2];
    else if (i < WS_W4) v = W3[i - WS_W3];
    else if (i < WS_WO) v = W4[i - WS_W4];
    else                v = Wo[i - WS_WO];
    ws[i] = f2bf(v);
  }
}

__global__ __launch_bounds__(256, 1) void snn_fused(
    const float* __restrict__ x,             // [2048][150][20] f32
    const unsigned short* __restrict__ wsb,  // bf16 weights (d_ws)
    const float* __restrict__ b1,            // [256] f32
    const float* __restrict__ b2,
    const float* __restrict__ b3,
    const float* __restrict__ b4,
    float* __restrict__ out)                 // [2048][200] f32
{
  __shared__ unsigned short A[TP * AP];   // 84480 B: spikes (bf16 0/1), in-place
  __shared__ float sc[16 * SCS];          // 16768 B: C bounce / mo / acc merge
  __shared__ unsigned short xa[TP * XAP]; // 12800 B: padded bf16 x for layer 1

  const int tid  = threadIdx.x;
  const int lane = tid & 63;
  const int wave = tid >> 6;
  const int c16  = lane & 15;   // MFMA: A row m / B col n / C col
  const int quad = lane >> 4;   // MFMA: k-chunk (A/B), row-group (C)
  const int bidx = blockIdx.x;

  const unsigned short* W1b = wsb + WS_W1;
  const unsigned short* W2b = wsb + WS_W2;
  const unsigned short* W3b = wsb + WS_W3;
  const unsigned short* W4b = wsb + WS_W4;
  const unsigned short* Wob = wsb + WS_WO;

  // ---- init: zero x staging (k-pad must be 0) and spike rows 150..159 ----
  for (int i = tid; i < TP * XAP; i += 256) xa[i] = 0;
  for (int i = tid; i < 10 * AP; i += 256) A[150 * AP + i] = 0;
  __syncthreads();
  const float* xb = x + (size_t)bidx * (T_N * DIN);
  for (int e = tid; e < T_N * DIN; e += 256) {
    int t = e / DIN;
    int i = e - t * DIN;
    xa[t * XAP + i] = f2bf(xb[e]);
  }

  // ---- layer 1: B-frags (K=20 padded to 32, zero pad) ----
  s16x8 wf1[4];
  #pragma unroll
  for (int i = 0; i < 4; ++i) {
    int n = (wave * 4 + i) * 16 + c16;
    #pragma unroll
    for (int j = 0; j < 8; ++j) {
      int k = quad * 8 + j;
      wf1[i][j] = (k < DIN) ? (short)W1b[n * DIN + k] : (short)0;
    }
  }
  {
    float bias = b1[tid];
    float m = 0.0f;
    __syncthreads();  // xa staged
    for (int mt = 0; mt < NMT; ++mt) {
      const s16x8 af = *(const s16x8*)&xa[(mt * 16 + c16) * XAP + quad * 8];
      f32x4 c[4];
      #pragma unroll
      for (int i = 0; i < 4; ++i) { f32x4 z = {0.f, 0.f, 0.f, 0.f}; c[i] = z; }
      #pragma unroll
      for (int i = 0; i < 4; ++i)
        c[i] = __builtin_amdgcn_mfma_f32_16x16x32_bf16(af, wf1[i], c[i], 0, 0, 0);
      #pragma unroll
      for (int i = 0; i < 4; ++i) {
        int col = (wave * 4 + i) * 16 + c16;
        #pragma unroll
        for (int g = 0; g < 4; ++g) sc[(quad * 4 + g) * SCS + col] = c[i][g];
      }
      __syncthreads();
      #pragma unroll
      for (int r = 0; r < 16; ++r) {
        int t = mt * 16 + r;
        if (t < T_N) {
          float inp = sc[r * SCS + tid] + bias;
          float reset = (m > 1.0f) ? 1.0f : 0.0f;
          m = 0.9f * m + inp - reset;
          A[t * AP + tid] = (m > 1.0f) ? (unsigned short)0x3F80 : (unsigned short)0;
        }
      }
      __syncthreads();
    }
  }

  // ---- layers 2..4: S <- spike(scan(S @ Wl^T + bl)), in place ----
  const unsigned short* Ws[3] = {W2b, W3b, W4b};
  const float* bs[3] = {b2, b3, b4};
  for (int l = 0; l < 3; ++l) {
    const unsigned short* wl = Ws[l];
    s16x8 wf[4][8];
    #pragma unroll
    for (int i = 0; i < 4; ++i) {
      int n = (wave * 4 + i) * 16 + c16;
      #pragma unroll
      for (int ks = 0; ks < 8; ++ks)
        wf[i][ks] = *(const s16x8*)(wl + n * H + ks * 32 + quad * 8);
    }
    float bias = bs[l][tid];
    float m = 0.0f;
    for (int mt = 0; mt < NMT; ++mt) {
      s16x8 af[8];
      const int abase = (mt * 16 + c16) * AP + quad * 8;
      #pragma unroll
      for (int ks = 0; ks < 8; ++ks) af[ks] = *(const s16x8*)&A[abase + ks * 32];
      f32x4 c[4];
      #pragma unroll
      for (int i = 0; i < 4; ++i) { f32x4 z = {0.f, 0.f, 0.f, 0.f}; c[i] = z; }
      #pragma unroll
      for (int ks = 0; ks < 8; ++ks) {
        #pragma unroll
        for (int i = 0; i < 4; ++i)
          c[i] = __builtin_amdgcn_mfma_f32_16x16x32_bf16(af[ks], wf[i][ks], c[i], 0, 0, 0);
      }
      #pragma unroll
      for (int i = 0; i < 4; ++i) {
        int col = (wave * 4 + i) * 16 + c16;
        #pragma unroll
        for (int g = 0; g < 4; ++g) sc[(quad * 4 + g) * SCS + col] = c[i][g];
      }
      __syncthreads();
      #pragma unroll
      for (int r = 0; r < 16; ++r) {
        int t = mt * 16 + r;
        if (t < T_N) {
          float inp = sc[r * SCS + tid] + bias;
          float reset = (m > 1.0f) ? 1.0f : 0.0f;
          m = 0.9f * m + inp - reset;
          A[t * AP + tid] = (m > 1.0f) ? (unsigned short)0x3F80 : (unsigned short)0;
        }
      }
      __syncthreads();
    }
  }

  // ---- output layer: mo scan + softmax accumulation (t > 50) ----
  {
    s16x8 wo[4][8];
    #pragma unroll
    for (int i = 0; i < 4; ++i) {
      int tile = wave + 4 * i;          // waves cover tiles 0..15; >=13 are dead
      int n = tile * 16 + c16;
      bool valid = (tile < 13) && (n < NOUT);
      #pragma unroll
      for (int ks = 0; ks < 8; ++ks) {
        if (valid) wo[i][ks] = *(const s16x8*)(Wob + n * H + ks * 32 + quad * 8);
        else       { s16x8 z = {0,0,0,0,0,0,0,0}; wo[i][ks] = z; }
      }
    }
    float mo = 0.0f;
    float acc0 = 0.f, acc1 = 0.f, acc2 = 0.f, acc3 = 0.f;
    for (int mt = 0; mt < NMT; ++mt) {
      s16x8 af[8];
      const int abase = (mt * 16 + c16) * AP + quad * 8;
      #pragma unroll
      for (int ks = 0; ks < 8; ++ks) af[ks] = *(const s16x8*)&A[abase + ks * 32];
      f32x4 c[4];
      #pragma unroll
      for (int i = 0; i < 4; ++i) { f32x4 z = {0.f, 0.f, 0.f, 0.f}; c[i] = z; }
      #pragma unroll
      for (int ks = 0; ks < 8; ++ks) {
        #pragma unroll
        for (int i = 0; i < 4; ++i)
          c[i] = __builtin_amdgcn_mfma_f32_16x16x32_bf16(af[ks], wo[i][ks], c[i], 0, 0, 0);
      }
      #pragma unroll
      for (int i = 0; i < 4; ++i) {
        int col = (wave + 4 * i) * 16 + c16;   // dead tiles land in cols 208..255 (unread)
        #pragma unroll
        for (int g = 0; g < 4; ++g) sc[(quad * 4 + g) * SCS + col] = c[i][g];
      }
      __syncthreads();
      // mo membrane scan (thread n owns out-neuron n; cols 200..207 get zero input)
      #pragma unroll
      for (int r = 0; r < 16; ++r) {
        int t = mt * 16 + r;
        if (t < T_N && tid < 208) {
          float inp = sc[r * SCS + tid];
          float reset = (mo > 1.0f) ? 1.0f : 0.0f;
          mo = 0.9f * mo + inp - reset;
          sc[r * SCS + tid] = mo;          // write back post-scan membrane
        }
      }
      __syncthreads();
      // softmax per t-row, rows {wave, wave+4, wave+8, wave+12}
      #pragma unroll
      for (int rr = 0; rr < 4; ++rr) {
        int r = wave + 4 * rr;
        int t = mt * 16 + r;
        if (t > 50 && t < T_N) {          // wave-uniform condition
          float v0 = sc[r * SCS + lane];
          float v1 = sc[r * SCS + 64 + lane];
          float v2 = sc[r * SCS + 128 + lane];
          bool has3 = (lane < 8);          // n = 192+lane valid only for n<200
          float v3 = has3 ? sc[r * SCS + 192 + lane] : -INFINITY;
          float mx = fmaxf(fmaxf(v0, v1), fmaxf(v2, v3));
          #pragma unroll
          for (int d = 32; d >= 1; d >>= 1) mx = fmaxf(mx, __shfl_xor(mx, d));
          float e0 = __expf(v0 - mx), e1 = __expf(v1 - mx), e2 = __expf(v2 - mx);
          float e3 = has3 ? __expf(v3 - mx) : 0.0f;
          float s = e0 + e1 + e2 + e3;
          #pragma unroll
          for (int d = 32; d >= 1; d >>= 1) s += __shfl_xor(s, d);
          float inv = 1.0f / s;
          acc0 += e0 * inv; acc1 += e1 * inv; acc2 += e2 * inv; acc3 += e3 * inv;
        }
      }
      __syncthreads();
    }
    // merge per-wave accumulators and store (f32 output!)
    sc[wave * SCS + lane]       = acc0;
    sc[wave * SCS + 64 + lane]  = acc1;
    sc[wave * SCS + 128 + lane] = acc2;
    if (lane < 8) sc[wave * SCS + 192 + lane] = acc3;
    __syncthreads();
    if (tid < NOUT) {
      float v = sc[tid] + sc[SCS + tid] + sc[2 * SCS + tid] + sc[3 * SCS + tid];
      out[(size_t)bidx * NOUT + tid] = v;
    }
  }
}

extern "C" void kernel_launch(void* const* d_in, const int* in_sizes, int n_in,
                              void* d_out, int out_size, void* d_ws, size_t ws_size,
                              hipStream_t stream) {
  (void)in_sizes; (void)n_in; (void)ws_size; (void)out_size;
  unsigned short* wsb = (unsigned short*)d_ws;
  cvt_weights<<<256, 256, 0, stream>>>(
      (const float*)d_in[1], (const float*)d_in[3], (const float*)d_in[5],
      (const float*)d_in[7], (const float*)d_in[9], wsb);
  snn_fused<<<2048, 256, 0, stream>>>(
      (const float*)d_in[0], wsb,
      (const float*)d_in[2], (const float*)d_in[4],
      (const float*)d_in[6], (const float*)d_in[8],
      (float*)d_out);
}

// Round 4
// 486.871 us; speedup vs baseline: 1.4362x; 1.4362x over previous
//
#include <hip/hip_runtime.h>
#include <hip/hip_bf16.h>
#include <math.h>

// SNN forward, fused per batch element. Inputs f32, output f32 [2048][200].
// R4: spike matrix BIT-PACKED in LDS (ballot-write, cooperative expand to a
// double-buffered bf16 tile) -> LDS 114KB -> 39.8KB -> 3+ blocks/CU.
// grid=2048 (one block per batch row), 256 threads (4 waves).

#define T_N 150
#define DIN 20
#define H 256
#define NOUT 200
#define NMT 10
#define AP 264      // Atile row stride (bf16): 528 B = 33*16 (b128-aligned), %32 banks balanced
#define SCS 258     // sc row stride (f32): 2-way max on writes, 2-way on reads
#define XAP 40      // xa row stride (bf16): 80 B, b128-aligned
#define BITS_W 10   // bits row stride (dwords): 40 B, b64-aligned for ballot writes

// bf16 weight offsets inside d_ws (elements)
#define WS_W1 0
#define WS_W2 5120
#define WS_W3 70656
#define WS_W4 136192
#define WS_WO 201728
#define WS_TOT 252928

typedef short s16x8 __attribute__((ext_vector_type(8)));
typedef float f32x4 __attribute__((ext_vector_type(4)));
typedef unsigned int u32x4 __attribute__((ext_vector_type(4)));

__device__ __forceinline__ unsigned short f2bf(float f) {
  union { float f; unsigned int i; } v; v.f = f;
  unsigned int r = v.i + 0x7FFFu + ((v.i >> 16) & 1u);
  return (unsigned short)(r >> 16);
}

__global__ void cvt_weights(const float* __restrict__ W1, const float* __restrict__ W2,
                            const float* __restrict__ W3, const float* __restrict__ W4,
                            const float* __restrict__ Wo, unsigned short* __restrict__ ws) {
  int idx = blockIdx.x * blockDim.x + threadIdx.x;
  int stride = gridDim.x * blockDim.x;
  for (int i = idx; i < WS_TOT; i += stride) {
    float v;
    if (i < WS_W2)      v = W1[i - WS_W1];
    else if (i < WS_W3) v = W2[i - WS_W2];
    else if (i < WS_W4) v = W3[i - WS_W3];
    else if (i < WS_WO) v = W4[i - WS_W4];
    else                v = Wo[i - WS_WO];
    ws[i] = f2bf(v);
  }
}

__global__ __launch_bounds__(256, 3) void snn_fused(
    const float* __restrict__ x,             // [2048][150][20] f32
    const unsigned short* __restrict__ wsb,  // bf16 weights (d_ws)
    const float* __restrict__ b1,            // [256] f32
    const float* __restrict__ b2,
    const float* __restrict__ b3,
    const float* __restrict__ b4,
    float* __restrict__ out)                 // [2048][200] f32
{
  __shared__ unsigned short Atile[2 * 16 * AP];  // 16896 B (buf0/buf1); aliases xa (12800 B)
  __shared__ float sc[16 * SCS];                 // 16512 B: C bounce / mo / acc merge
  __shared__ unsigned int bits[160 * BITS_W];    // 6400 B: bit-packed spikes, in-place

  const int tid  = threadIdx.x;
  const int lane = tid & 63;
  const int wave = tid >> 6;
  const int c16  = lane & 15;   // MFMA: A row m / B col n / C col
  const int quad = lane >> 4;   // MFMA: k-chunk (A/B), row-group (C)
  const int bidx = blockIdx.x;

  unsigned short* xa = Atile;   // layer-1 staging aliases Atile (disjoint lifetime)

  const unsigned short* W1b = wsb + WS_W1;
  const unsigned short* W2b = wsb + WS_W2;
  const unsigned short* W3b = wsb + WS_W3;
  const unsigned short* W4b = wsb + WS_W4;
  const unsigned short* Wob = wsb + WS_WO;

  // expand bit-packed spike rows [mt*16, +16) into Atile[buf] as bf16 0/1
  auto expand_tile = [&](int mt, int buf) {
    int r = tid >> 4, g = tid & 15;
    unsigned int w = bits[(mt * 16 + r) * BITS_W + (g >> 1)];
    if (g & 1) w >>= 16;
    unsigned int o[8];
    #pragma unroll
    for (int k = 0; k < 8; ++k) {
      unsigned int blo = (w >> (2 * k)) & 1u;
      unsigned int bhi = (w >> (2 * k + 1)) & 1u;
      o[k] = blo * 0x3F80u + bhi * 0x3F800000u;
    }
    u32x4 lo = {o[0], o[1], o[2], o[3]};
    u32x4 hi = {o[4], o[5], o[6], o[7]};
    unsigned short* dst = &Atile[buf * (16 * AP) + r * AP + g * 16];
    *(u32x4*)dst = lo;
    *(u32x4*)(dst + 8) = hi;
  };

  // ---- init: zero Atile/xa union (pads must be 0) and bits (rows 150-159 stay 0) ----
  for (int i = tid; i < (2 * 16 * AP) / 2; i += 256) ((unsigned int*)Atile)[i] = 0;
  for (int i = tid; i < 160 * BITS_W; i += 256) bits[i] = 0;
  __syncthreads();
  const float* xb = x + (size_t)bidx * (T_N * DIN);
  for (int e = tid; e < T_N * DIN; e += 256) {
    int t = e / DIN;
    int i = e - t * DIN;
    xa[t * XAP + i] = f2bf(xb[e]);
  }

  // ---- layer 1: x @ W1^T (K=20 pad 32), scan -> ballot -> bits ----
  {
    s16x8 wf1[4];
    #pragma unroll
    for (int i = 0; i < 4; ++i) {
      int n = (wave * 4 + i) * 16 + c16;
      #pragma unroll
      for (int j = 0; j < 8; ++j) {
        int k = quad * 8 + j;
        wf1[i][j] = (k < DIN) ? (short)W1b[n * DIN + k] : (short)0;
      }
    }
    float bias = b1[tid];
    float m = 0.0f;
    __syncthreads();  // xa staged
    for (int mt = 0; mt < NMT; ++mt) {
      const s16x8 af = *(const s16x8*)&xa[(mt * 16 + c16) * XAP + quad * 8];
      f32x4 c[4];
      #pragma unroll
      for (int i = 0; i < 4; ++i) { f32x4 z = {0.f, 0.f, 0.f, 0.f}; c[i] = z; }
      #pragma unroll
      for (int i = 0; i < 4; ++i)
        c[i] = __builtin_amdgcn_mfma_f32_16x16x32_bf16(af, wf1[i], c[i], 0, 0, 0);
      #pragma unroll
      for (int i = 0; i < 4; ++i) {
        int col = (wave * 4 + i) * 16 + c16;
        #pragma unroll
        for (int g = 0; g < 4; ++g) sc[(quad * 4 + g) * SCS + col] = c[i][g];
      }
      __syncthreads();
      #pragma unroll
      for (int r = 0; r < 16; ++r) {
        int t = mt * 16 + r;
        if (t < T_N) {  // block-uniform
          float inp = sc[r * SCS + tid] + bias;
          float reset = (m > 1.0f) ? 1.0f : 0.0f;
          m = 0.9f * m + inp - reset;
          unsigned long long msk = __ballot(m > 1.0f);
          if (lane == 0) *(unsigned long long*)&bits[t * BITS_W + wave * 2] = msk;
        }
      }
      __syncthreads();
    }
  }

  // ---- layers 2..4: bits -> expand -> GEMM -> scan -> ballot -> bits (in place) ----
  const unsigned short* Ws[3] = {W2b, W3b, W4b};
  const float* bs[3] = {b2, b3, b4};
  for (int l = 0; l < 3; ++l) {
    const unsigned short* wl = Ws[l];
    s16x8 wf[4][8];
    #pragma unroll
    for (int i = 0; i < 4; ++i) {
      int n = (wave * 4 + i) * 16 + c16;
      #pragma unroll
      for (int ks = 0; ks < 8; ++ks)
        wf[i][ks] = *(const s16x8*)(wl + n * H + ks * 32 + quad * 8);
    }
    float bias = bs[l][tid];
    float m = 0.0f;
    expand_tile(0, 0);
    __syncthreads();
    for (int mt = 0; mt < NMT; ++mt) {
      int cur = mt & 1;
      if (mt < NMT - 1) expand_tile(mt + 1, cur ^ 1);   // prefetch-expand next tile
      s16x8 af[8];
      const unsigned short* abase = &Atile[cur * (16 * AP) + c16 * AP + quad * 8];
      #pragma unroll
      for (int ks = 0; ks < 8; ++ks) af[ks] = *(const s16x8*)(abase + ks * 32);
      f32x4 c[4];
      #pragma unroll
      for (int i = 0; i < 4; ++i) { f32x4 z = {0.f, 0.f, 0.f, 0.f}; c[i] = z; }
      #pragma unroll
      for (int ks = 0; ks < 8; ++ks) {
        #pragma unroll
        for (int i = 0; i < 4; ++i)
          c[i] = __builtin_amdgcn_mfma_f32_16x16x32_bf16(af[ks], wf[i][ks], c[i], 0, 0, 0);
      }
      #pragma unroll
      for (int i = 0; i < 4; ++i) {
        int col = (wave * 4 + i) * 16 + c16;
        #pragma unroll
        for (int g = 0; g < 4; ++g) sc[(quad * 4 + g) * SCS + col] = c[i][g];
      }
      __syncthreads();
      #pragma unroll
      for (int r = 0; r < 16; ++r) {
        int t = mt * 16 + r;
        if (t < T_N) {
          float inp = sc[r * SCS + tid] + bias;
          float reset = (m > 1.0f) ? 1.0f : 0.0f;
          m = 0.9f * m + inp - reset;
          unsigned long long msk = __ballot(m > 1.0f);
          if (lane == 0) *(unsigned long long*)&bits[t * BITS_W + wave * 2] = msk;
        }
      }
      __syncthreads();
    }
  }

  // ---- output layer: mo scan + softmax accumulation (t > 50) ----
  {
    s16x8 wo[4][8];
    #pragma unroll
    for (int i = 0; i < 4; ++i) {
      int tile = wave + 4 * i;          // waves cover tiles 0..15; >=13 are dead
      int n = tile * 16 + c16;
      bool valid = (tile < 13) && (n < NOUT);
      #pragma unroll
      for (int ks = 0; ks < 8; ++ks) {
        if (valid) wo[i][ks] = *(const s16x8*)(Wob + n * H + ks * 32 + quad * 8);
        else       { s16x8 z = {0,0,0,0,0,0,0,0}; wo[i][ks] = z; }
      }
    }
    float mo = 0.0f;
    float acc0 = 0.f, acc1 = 0.f, acc2 = 0.f, acc3 = 0.f;
    expand_tile(0, 0);
    __syncthreads();
    for (int mt = 0; mt < NMT; ++mt) {
      int cur = mt & 1;
      if (mt < NMT - 1) expand_tile(mt + 1, cur ^ 1);
      s16x8 af[8];
      const unsigned short* abase = &Atile[cur * (16 * AP) + c16 * AP + quad * 8];
      #pragma unroll
      for (int ks = 0; ks < 8; ++ks) af[ks] = *(const s16x8*)(abase + ks * 32);
      f32x4 c[4];
      #pragma unroll
      for (int i = 0; i < 4; ++i) { f32x4 z = {0.f, 0.f, 0.f, 0.f}; c[i] = z; }
      #pragma unroll
      for (int ks = 0; ks < 8; ++ks) {
        #pragma unroll
        for (int i = 0; i < 4; ++i)
          c[i] = __builtin_amdgcn_mfma_f32_16x16x32_bf16(af[ks], wo[i][ks], c[i], 0, 0, 0);
      }
      #pragma unroll
      for (int i = 0; i < 4; ++i) {
        int col = (wave + 4 * i) * 16 + c16;   // dead tiles land in cols 208..255 (unread)
        #pragma unroll
        for (int g = 0; g < 4; ++g) sc[(quad * 4 + g) * SCS + col] = c[i][g];
      }
      __syncthreads();
      // mo membrane scan (thread n owns out-neuron n; cols 200..207 get zero input)
      #pragma unroll
      for (int r = 0; r < 16; ++r) {
        int t = mt * 16 + r;
        if (t < T_N && tid < 208) {
          float inp = sc[r * SCS + tid];
          float reset = (mo > 1.0f) ? 1.0f : 0.0f;
          mo = 0.9f * mo + inp - reset;
          sc[r * SCS + tid] = mo;          // write back post-scan membrane
        }
      }
      __syncthreads();
      // softmax per t-row, rows {wave, wave+4, wave+8, wave+12}
      #pragma unroll
      for (int rr = 0; rr < 4; ++rr) {
        int r = wave + 4 * rr;
        int t = mt * 16 + r;
        if (t > 50 && t < T_N) {          // wave-uniform condition
          float v0 = sc[r * SCS + lane];
          float v1 = sc[r * SCS + 64 + lane];
          float v2 = sc[r * SCS + 128 + lane];
          bool has3 = (lane < 8);          // n = 192+lane valid only for n<200
          float v3 = has3 ? sc[r * SCS + 192 + lane] : -INFINITY;
          float mx = fmaxf(fmaxf(v0, v1), fmaxf(v2, v3));
          #pragma unroll
          for (int d = 32; d >= 1; d >>= 1) mx = fmaxf(mx, __shfl_xor(mx, d));
          float e0 = __expf(v0 - mx), e1 = __expf(v1 - mx), e2 = __expf(v2 - mx);
          float e3 = has3 ? __expf(v3 - mx) : 0.0f;
          float s = e0 + e1 + e2 + e3;
          #pragma unroll
          for (int d = 32; d >= 1; d >>= 1) s += __shfl_xor(s, d);
          float inv = 1.0f / s;
          acc0 += e0 * inv; acc1 += e1 * inv; acc2 += e2 * inv; acc3 += e3 * inv;
        }
      }
      __syncthreads();
    }
    // merge per-wave accumulators and store (f32 output)
    sc[wave * SCS + lane]       = acc0;
    sc[wave * SCS + 64 + lane]  = acc1;
    sc[wave * SCS + 128 + lane] = acc2;
    if (lane < 8) sc[wave * SCS + 192 + lane] = acc3;
    __syncthreads();
    if (tid < NOUT) {
      float v = sc[tid] + sc[SCS + tid] + sc[2 * SCS + tid] + sc[3 * SCS + tid];
      out[(size_t)bidx * NOUT + tid] = v;
    }
  }
}

extern "C" void kernel_launch(void* const* d_in, const int* in_sizes, int n_in,
                              void* d_out, int out_size, void* d_ws, size_t ws_size,
                              hipStream_t stream) {
  (void)in_sizes; (void)n_in; (void)ws_size; (void)out_size;
  unsigned short* wsb = (unsigned short*)d_ws;
  cvt_weights<<<256, 256, 0, stream>>>(
      (const float*)d_in[1], (const float*)d_in[3], (const float*)d_in[5],
      (const float*)d_in[7], (const float*)d_in[9], wsb);
  snn_fused<<<2048, 256, 0, stream>>>(
      (const float*)d_in[0], wsb,
      (const float*)d_in[2], (const float*)d_in[4],
      (const float*)d_in[6], (const float*)d_in[8],
      (float*)d_out);
}

// Round 5
// 460.012 us; speedup vs baseline: 1.5200x; 1.0584x over previous
//
#include <hip/hip_runtime.h>
#include <math.h>

// SNN forward, fused per batch element. Inputs f32, output f32 [2048][200].
// R5: 512-thread blocks (8 waves, 2 N-tiles/wave -> 64 weight VGPRs, no spill,
// launch_bounds(512,4) -> 2 blocks/CU = 50% occupancy) + software-pipelined
// tile loop (double-buffered sc: GEMM(mt) || expand(mt+1) || scan(mt-1), ONE
// barrier per tile). Spikes bit-packed in LDS (ballot write, coop expand).

#define T_N 150
#define DIN 20
#define H 256
#define NOUT 200
#define NMT 10
#define AP 264      // Atile row stride (bf16): 528 B, 16B-aligned, 2-way banks max
#define SCS 258     // sc row stride (f32): writes/reads 2-way max
#define XAP 40      // xa row stride (bf16)
#define BW 10       // bits row stride (dwords): 40 B (8B-aligned ballot writes)

// bf16 weight offsets inside d_ws (elements)
#define WS_W1 0
#define WS_W2 5120
#define WS_W3 70656
#define WS_W4 136192
#define WS_WO 201728
#define WS_TOT 252928

typedef short s16x8 __attribute__((ext_vector_type(8)));
typedef float f32x4 __attribute__((ext_vector_type(4)));
typedef unsigned int u32x4 __attribute__((ext_vector_type(4)));

__device__ __forceinline__ unsigned short f2bf(float f) {
  union { float f; unsigned int i; } v; v.f = f;
  unsigned int r = v.i + 0x7FFFu + ((v.i >> 16) & 1u);
  return (unsigned short)(r >> 16);
}

__global__ void cvt_weights(const float* __restrict__ W1, const float* __restrict__ W2,
                            const float* __restrict__ W3, const float* __restrict__ W4,
                            const float* __restrict__ Wo, unsigned short* __restrict__ ws) {
  int idx = blockIdx.x * blockDim.x + threadIdx.x;
  int stride = gridDim.x * blockDim.x;
  for (int i = idx; i < WS_TOT; i += stride) {
    float v;
    if (i < WS_W2)      v = W1[i - WS_W1];
    else if (i < WS_W3) v = W2[i - WS_W2];
    else if (i < WS_W4) v = W3[i - WS_W3];
    else if (i < WS_WO) v = W4[i - WS_W4];
    else                v = Wo[i - WS_WO];
    ws[i] = f2bf(v);
  }
}

__global__ __launch_bounds__(512, 4) void snn_fused(
    const float* __restrict__ x,             // [2048][150][20] f32
    const unsigned short* __restrict__ wsb,  // bf16 weights (d_ws)
    const float* __restrict__ b1,            // [256] f32
    const float* __restrict__ b2,
    const float* __restrict__ b3,
    const float* __restrict__ b4,
    float* __restrict__ out)                 // [2048][200] f32
{
  __shared__ unsigned short Atile[2 * 16 * AP];  // 16896 B, double-buffered; aliases xa
  __shared__ float sc[2 * 16 * SCS];             // 33024 B, double-buffered C bounce
  __shared__ unsigned int bits[160 * BW];        // 6400 B, bit-packed spikes (in place)

  const int tid  = threadIdx.x;
  const int lane = tid & 63;
  const int wave = tid >> 6;    // 0..7
  const int c16  = lane & 15;   // MFMA: A row m / B col n / C col
  const int quad = lane >> 4;   // MFMA: k-chunk (A/B), row-group (C)
  const int bidx = blockIdx.x;

  unsigned short* xa = Atile;   // layer-1 x staging (12800 B) aliases Atile

  const unsigned short* W1b = wsb + WS_W1;
  const unsigned short* Wob = wsb + WS_WO;

  // expand bit-packed rows [mt*16,+16) into Atile[buf]: 512 thr x 8 cols each
  auto expand_tile = [&](int mt, int buf) {
    int r = tid >> 5, cg = tid & 31;
    unsigned int w = bits[(mt * 16 + r) * BW + (cg >> 2)];
    unsigned int b = (w >> ((cg & 3) * 8)) & 0xFFu;
    unsigned int o[4];
    #pragma unroll
    for (int j = 0; j < 4; ++j) {
      unsigned int blo = (b >> (2 * j)) & 1u;
      unsigned int bhi = (b >> (2 * j + 1)) & 1u;
      o[j] = blo * 0x3F80u + bhi * 0x3F800000u;
    }
    u32x4 v = {o[0], o[1], o[2], o[3]};
    *(u32x4*)&Atile[buf * (16 * AP) + r * AP + cg * 8] = v;
  };

  // membrane scan of tile mt from sc[sb], ballot spikes into bits (waves 0-3)
  auto scan_tile = [&](int mt, int sb, float bias, float& m) {
    if (tid < 256) {
      #pragma unroll
      for (int r = 0; r < 16; ++r) {
        int t = mt * 16 + r;
        if (t < T_N) {
          float inp = sc[sb * (16 * SCS) + r * SCS + tid] + bias;
          float reset = (m > 1.0f) ? 1.0f : 0.0f;
          m = 0.9f * m + inp - reset;
          unsigned long long msk = __ballot(m > 1.0f);
          if (lane == 0) *(unsigned long long*)&bits[t * BW + wave * 2] = msk;
        }
      }
    }
  };

  auto store_c = [&](int sb, f32x4* c) {
    #pragma unroll
    for (int i = 0; i < 2; ++i) {
      int col = (2 * wave + i) * 16 + c16;
      #pragma unroll
      for (int g = 0; g < 4; ++g)
        sc[sb * (16 * SCS) + (quad * 4 + g) * SCS + col] = c[i][g];
    }
  };

  // ---- init: zero Atile/xa (pads must be 0) and bits (rows 150-159 stay 0) ----
  for (int i = tid; i < (2 * 16 * AP) / 2; i += 512) ((unsigned int*)Atile)[i] = 0;
  for (int i = tid; i < 160 * BW; i += 512) bits[i] = 0;
  __syncthreads();
  const float* xb = x + (size_t)bidx * (T_N * DIN);
  for (int e = tid; e < T_N * DIN; e += 512) {
    int t = e / DIN;
    int i = e - t * DIN;
    xa[t * XAP + i] = f2bf(xb[e]);
  }

  float m = 0.0f;
  float bias = (tid < 256) ? b1[tid] : 0.0f;

  // ---- layer 1: x @ W1^T (K=20 pad 32), pipelined GEMM || scan ----
  {
    s16x8 wf1[2];
    #pragma unroll
    for (int i = 0; i < 2; ++i) {
      int n = (2 * wave + i) * 16 + c16;
      #pragma unroll
      for (int j = 0; j < 8; ++j) {
        int k = quad * 8 + j;
        wf1[i][j] = (k < DIN) ? (short)W1b[n * DIN + k] : (short)0;
      }
    }
    __syncthreads();  // xa staged
    for (int mt = 0; mt < NMT; ++mt) {
      const s16x8 a1 = *(const s16x8*)&xa[(mt * 16 + c16) * XAP + quad * 8];
      f32x4 c[2];
      #pragma unroll
      for (int i = 0; i < 2; ++i) { f32x4 z = {0.f, 0.f, 0.f, 0.f}; c[i] = z; }
      c[0] = __builtin_amdgcn_mfma_f32_16x16x32_bf16(a1, wf1[0], c[0], 0, 0, 0);
      c[1] = __builtin_amdgcn_mfma_f32_16x16x32_bf16(a1, wf1[1], c[1], 0, 0, 0);
      if (mt > 0) scan_tile(mt - 1, (mt - 1) & 1, bias, m);
      store_c(mt & 1, c);
      __syncthreads();
    }
    // pending: scan(9) on sc[1] -> merged into next layer's prologue
  }

  // ---- layers 2..4: pipelined expand || GEMM || scan, 1 barrier/tile ----
  const float* bsl[3] = {b2, b3, b4};
  const int wofs[3] = {WS_W2, WS_W3, WS_W4};
  for (int l = 0; l < 3; ++l) {
    const unsigned short* wl = wsb + wofs[l];
    s16x8 wf[2][8];
    #pragma unroll
    for (int i = 0; i < 2; ++i) {
      int n = (2 * wave + i) * 16 + c16;
      #pragma unroll
      for (int ks = 0; ks < 8; ++ks)
        wf[i][ks] = *(const s16x8*)(wl + n * H + ks * 32 + quad * 8);
    }
    expand_tile(0, 0);                 // reads prev-layer bits tile 0
    scan_tile(9, 1, bias, m);          // finish PREV layer's last tile (prev bias/m)
    __syncthreads();
    bias = (tid < 256) ? bsl[l][tid] : 0.0f;
    m = 0.0f;
    for (int mt = 0; mt < NMT; ++mt) {
      f32x4 c[2];
      #pragma unroll
      for (int i = 0; i < 2; ++i) { f32x4 z = {0.f, 0.f, 0.f, 0.f}; c[i] = z; }
      const unsigned short* ab = &Atile[(mt & 1) * (16 * AP) + c16 * AP + quad * 8];
      #pragma unroll
      for (int b = 0; b < 2; ++b) {
        s16x8 af[4];
        #pragma unroll
        for (int k = 0; k < 4; ++k) af[k] = *(const s16x8*)(ab + (4 * b + k) * 32);
        #pragma unroll
        for (int k = 0; k < 4; ++k) {
          c[0] = __builtin_amdgcn_mfma_f32_16x16x32_bf16(af[k], wf[0][4 * b + k], c[0], 0, 0, 0);
          c[1] = __builtin_amdgcn_mfma_f32_16x16x32_bf16(af[k], wf[1][4 * b + k], c[1], 0, 0, 0);
        }
      }
      if (mt < NMT - 1) expand_tile(mt + 1, (mt + 1) & 1);
      if (mt > 0) scan_tile(mt - 1, (mt - 1) & 1, bias, m);
      store_c(mt & 1, c);
      __syncthreads();
    }
    // pending: scan(9) on sc[1]
  }

  // ---- output layer: GEMM || mo-scan, then softmax accumulate (t > 50) ----
  {
    s16x8 wo[2][8];
    #pragma unroll
    for (int i = 0; i < 2; ++i) {
      int n = (2 * wave + i) * 16 + c16;
      bool valid = (n < NOUT);
      #pragma unroll
      for (int ks = 0; ks < 8; ++ks) {
        if (valid) wo[i][ks] = *(const s16x8*)(Wob + n * H + ks * 32 + quad * 8);
        else       { s16x8 z = {0,0,0,0,0,0,0,0}; wo[i][ks] = z; }
      }
    }
    expand_tile(0, 0);
    scan_tile(9, 1, bias, m);          // finish L4's last tile
    __syncthreads();

    float mo = 0.0f;
    float a0 = 0.f, a1 = 0.f, a2 = 0.f, a3 = 0.f;

    auto moscan = [&](int mt, int sb) {
      if (tid < 208) {
        #pragma unroll
        for (int r = 0; r < 16; ++r) {
          int t = mt * 16 + r;
          if (t < T_N) {
            float inp = sc[sb * (16 * SCS) + r * SCS + tid];
            float reset = (mo > 1.0f) ? 1.0f : 0.0f;
            mo = 0.9f * mo + inp - reset;
            sc[sb * (16 * SCS) + r * SCS + tid] = mo;   // post-scan membrane
          }
        }
      }
    };
    auto softmax_t = [&](int mt, int sb) {
      #pragma unroll
      for (int rr = 0; rr < 2; ++rr) {
        int r = 2 * wave + rr;
        int t = mt * 16 + r;
        if (t > 50 && t < T_N) {        // wave-uniform
          int base = sb * (16 * SCS) + r * SCS;
          float v0 = sc[base + lane];
          float v1 = sc[base + 64 + lane];
          float v2 = sc[base + 128 + lane];
          bool has3 = (lane < 8);        // n=192+lane valid only for n<200
          float v3 = has3 ? sc[base + 192 + lane] : -INFINITY;
          float mx = fmaxf(fmaxf(v0, v1), fmaxf(v2, v3));
          #pragma unroll
          for (int d = 32; d >= 1; d >>= 1) mx = fmaxf(mx, __shfl_xor(mx, d));
          float e0 = __expf(v0 - mx), e1 = __expf(v1 - mx), e2 = __expf(v2 - mx);
          float e3 = has3 ? __expf(v3 - mx) : 0.0f;
          float s = e0 + e1 + e2 + e3;
          #pragma unroll
          for (int d = 32; d >= 1; d >>= 1) s += __shfl_xor(s, d);
          float inv = 1.0f / s;
          a0 += e0 * inv; a1 += e1 * inv; a2 += e2 * inv; a3 += e3 * inv;
        }
      }
    };

    for (int mt = 0; mt < NMT; ++mt) {
      f32x4 c[2];
      #pragma unroll
      for (int i = 0; i < 2; ++i) { f32x4 z = {0.f, 0.f, 0.f, 0.f}; c[i] = z; }
      const unsigned short* ab = &Atile[(mt & 1) * (16 * AP) + c16 * AP + quad * 8];
      #pragma unroll
      for (int b = 0; b < 2; ++b) {
        s16x8 af[4];
        #pragma unroll
        for (int k = 0; k < 4; ++k) af[k] = *(const s16x8*)(ab + (4 * b + k) * 32);
        #pragma unroll
        for (int k = 0; k < 4; ++k) {
          c[0] = __builtin_amdgcn_mfma_f32_16x16x32_bf16(af[k], wo[0][4 * b + k], c[0], 0, 0, 0);
          c[1] = __builtin_amdgcn_mfma_f32_16x16x32_bf16(af[k], wo[1][4 * b + k], c[1], 0, 0, 0);
        }
      }
      if (mt < NMT - 1) expand_tile(mt + 1, (mt + 1) & 1);
      if (mt > 0) moscan(mt - 1, (mt - 1) & 1);
      store_c(mt & 1, c);
      __syncthreads();
      if (mt > 0) { softmax_t(mt - 1, (mt - 1) & 1); __syncthreads(); }
    }
    moscan(9, 1);  __syncthreads();
    softmax_t(9, 1); __syncthreads();

    // merge 8 per-wave accumulators via sc rows 0-7 (buffer 0), then store f32
    sc[wave * SCS + lane]        = a0;
    sc[wave * SCS + 64 + lane]   = a1;
    sc[wave * SCS + 128 + lane]  = a2;
    if (lane < 8) sc[wave * SCS + 192 + lane] = a3;
    __syncthreads();
    if (tid < NOUT) {
      float v = 0.f;
      #pragma unroll
      for (int w = 0; w < 8; ++w) v += sc[w * SCS + tid];
      out[(size_t)bidx * NOUT + tid] = v;
    }
  }
}

extern "C" void kernel_launch(void* const* d_in, const int* in_sizes, int n_in,
                              void* d_out, int out_size, void* d_ws, size_t ws_size,
                              hipStream_t stream) {
  (void)in_sizes; (void)n_in; (void)ws_size; (void)out_size;
  unsigned short* wsb = (unsigned short*)d_ws;
  cvt_weights<<<256, 256, 0, stream>>>(
      (const float*)d_in[1], (const float*)d_in[3], (const float*)d_in[5],
      (const float*)d_in[7], (const float*)d_in[9], wsb);
  snn_fused<<<2048, 512, 0, stream>>>(
      (const float*)d_in[0], wsb,
      (const float*)d_in[2], (const float*)d_in[4],
      (const float*)d_in[6], (const float*)d_in[8],
      (float*)d_out);
}

// Round 6
// 412.953 us; speedup vs baseline: 1.6932x; 1.1140x over previous
//
#include <hip/hip_runtime.h>
#include <math.h>

// SNN forward, fused per batch element. Inputs f32, output f32 [2048][200].
// R6: (a) column-major sc (b128 C-store + b128 scan reads), (b) weight frags
// pinned in VGPRs via empty inline asm (stop per-tile remat reloads),
// (c) bias folded into MFMA accumulator init. 512 thr / 8 waves / 2 blocks/CU.

#define T_N 150
#define DIN 20
#define H 256
#define NOUT 200
#define NMT 10
#define AP 264      // Atile row stride (bf16)
#define CST 20      // sc col stride (f32): 16 rows + 4 pad, 16B-aligned cols
#define SCB (256 * CST)  // sc buffer stride (5120 f32)
#define XAP 40      // xa row stride (bf16)
#define BW 10       // bits row stride (dwords)

#define WS_W1 0
#define WS_W2 5120
#define WS_W3 70656
#define WS_W4 136192
#define WS_WO 201728
#define WS_TOT 252928

typedef short s16x8 __attribute__((ext_vector_type(8)));
typedef float f32x4 __attribute__((ext_vector_type(4)));
typedef unsigned int u32x4 __attribute__((ext_vector_type(4)));

__device__ __forceinline__ unsigned short f2bf(float f) {
  union { float f; unsigned int i; } v; v.f = f;
  unsigned int r = v.i + 0x7FFFu + ((v.i >> 16) & 1u);
  return (unsigned short)(r >> 16);
}

__global__ void cvt_weights(const float* __restrict__ W1, const float* __restrict__ W2,
                            const float* __restrict__ W3, const float* __restrict__ W4,
                            const float* __restrict__ Wo, unsigned short* __restrict__ ws) {
  int idx = blockIdx.x * blockDim.x + threadIdx.x;
  int stride = gridDim.x * blockDim.x;
  for (int i = idx; i < WS_TOT; i += stride) {
    float v;
    if (i < WS_W2)      v = W1[i - WS_W1];
    else if (i < WS_W3) v = W2[i - WS_W2];
    else if (i < WS_W4) v = W3[i - WS_W3];
    else if (i < WS_WO) v = W4[i - WS_W4];
    else                v = Wo[i - WS_WO];
    ws[i] = f2bf(v);
  }
}

__global__ __launch_bounds__(512, 4) void snn_fused(
    const float* __restrict__ x,             // [2048][150][20] f32
    const unsigned short* __restrict__ wsb,  // bf16 weights (d_ws)
    const float* __restrict__ b1,            // [256] f32
    const float* __restrict__ b2,
    const float* __restrict__ b3,
    const float* __restrict__ b4,
    float* __restrict__ out)                 // [2048][200] f32
{
  __shared__ unsigned short Atile[2 * 16 * AP];  // 16896 B, double-buffered; aliases xa
  __shared__ float sc[2 * SCB];                  // 40960 B, col-major C bounce (dbuf)
  __shared__ unsigned int bits[160 * BW];        // 6400 B, bit-packed spikes (in place)
                                                 // total 64256 B -> 2 blocks/CU

  const int tid  = threadIdx.x;
  const int lane = tid & 63;
  const int wave = tid >> 6;    // 0..7
  const int c16  = lane & 15;   // MFMA: A row m / B col n / C col
  const int quad = lane >> 4;   // MFMA: k-chunk (A/B), row-group (C)
  const int bidx = blockIdx.x;
  const int col0 = 2 * wave * 16 + c16;   // this lane's first C column
  const int col1 = col0 + 16;             // second C column

  unsigned short* xa = Atile;   // layer-1 x staging (12800 B) aliases Atile

  // expand bit-packed rows [mt*16,+16) into Atile[buf]: 512 thr x 8 cols each
  auto expand_tile = [&](int mt, int buf) {
    int r = tid >> 5, cg = tid & 31;
    unsigned int w = bits[(mt * 16 + r) * BW + (cg >> 2)];
    unsigned int b = (w >> ((cg & 3) * 8)) & 0xFFu;
    unsigned int o[4];
    #pragma unroll
    for (int j = 0; j < 4; ++j) {
      unsigned int blo = (b >> (2 * j)) & 1u;
      unsigned int bhi = (b >> (2 * j + 1)) & 1u;
      o[j] = blo * 0x3F80u + bhi * 0x3F800000u;
    }
    u32x4 v = {o[0], o[1], o[2], o[3]};
    *(u32x4*)&Atile[buf * (16 * AP) + r * AP + cg * 8] = v;
  };

  // membrane scan of tile mt from sc[sb] (col-major), ballot -> bits
  auto scan_tile = [&](int mt, int sb, float& m) {
    if (tid < 256) {
      const f32x4* vp = (const f32x4*)&sc[sb * SCB + tid * CST];
      f32x4 v[4];
      #pragma unroll
      for (int j = 0; j < 4; ++j) v[j] = vp[j];
      #pragma unroll
      for (int r = 0; r < 16; ++r) {
        int t = mt * 16 + r;
        if (t < T_N) {
          float inp = v[r / 4][r % 4];     // bias already folded into GEMM C-init
          float reset = (m > 1.0f) ? 1.0f : 0.0f;
          m = 0.9f * m + inp - reset;
          unsigned long long msk = __ballot(m > 1.0f);
          if (lane == 0) *(unsigned long long*)&bits[t * BW + wave * 2] = msk;
        }
      }
    }
  };

  auto store_c = [&](int sb, f32x4 c0, f32x4 c1) {
    *(f32x4*)&sc[sb * SCB + col0 * CST + quad * 4] = c0;
    *(f32x4*)&sc[sb * SCB + col1 * CST + quad * 4] = c1;
  };

  // ---- init: zero Atile/xa (pads must be 0) and bits (rows 150-159 stay 0) ----
  for (int i = tid; i < (2 * 16 * AP) / 2; i += 512) ((unsigned int*)Atile)[i] = 0;
  for (int i = tid; i < 160 * BW; i += 512) bits[i] = 0;
  __syncthreads();
  const float* xb = x + (size_t)bidx * (T_N * DIN);
  for (int e = tid; e < T_N * DIN; e += 512) {
    int t = e / DIN;
    int i = e - t * DIN;
    xa[t * XAP + i] = f2bf(xb[e]);
  }

  float m = 0.0f;

  // ---- layer 1: x @ W1^T (K=20 pad 32), pipelined GEMM || scan ----
  {
    s16x8 w1f[2];
    #pragma unroll
    for (int i = 0; i < 2; ++i) {
      int n = (i == 0) ? col0 : col1;
      #pragma unroll
      for (int j = 0; j < 8; ++j) {
        int k = quad * 8 + j;
        w1f[i][j] = (k < DIN) ? (short)wsb[WS_W1 + n * DIN + k] : (short)0;
      }
      asm volatile("" : "+v"(w1f[i]));
    }
    float bc0 = b1[col0], bc1 = b1[col1];
    __syncthreads();  // xa staged
    for (int mt = 0; mt < NMT; ++mt) {
      const s16x8 a1 = *(const s16x8*)&xa[(mt * 16 + c16) * XAP + quad * 8];
      f32x4 c0 = {bc0, bc0, bc0, bc0};
      f32x4 c1 = {bc1, bc1, bc1, bc1};
      c0 = __builtin_amdgcn_mfma_f32_16x16x32_bf16(a1, w1f[0], c0, 0, 0, 0);
      c1 = __builtin_amdgcn_mfma_f32_16x16x32_bf16(a1, w1f[1], c1, 0, 0, 0);
      store_c(mt & 1, c0, c1);
      if (mt > 0) scan_tile(mt - 1, (mt - 1) & 1, m);
      __syncthreads();
    }
    // pending: scan(9) on sc[1] -> next layer's prologue
  }

  // ---- layers 2..4: pipelined expand || GEMM || scan, 1 barrier/tile ----
  const float* bsl[3] = {b2, b3, b4};
  const int wofs[3] = {WS_W2, WS_W3, WS_W4};
  for (int l = 0; l < 3; ++l) {
    const unsigned short* wl = wsb + wofs[l];
    s16x8 wf0[8], wf1[8];
    #pragma unroll
    for (int ks = 0; ks < 8; ++ks) {
      wf0[ks] = *(const s16x8*)(wl + col0 * H + ks * 32 + quad * 8);
      wf1[ks] = *(const s16x8*)(wl + col1 * H + ks * 32 + quad * 8);
      asm volatile("" : "+v"(wf0[ks]));
      asm volatile("" : "+v"(wf1[ks]));
    }
    float bc0 = bsl[l][col0], bc1 = bsl[l][col1];
    expand_tile(0, 0);                 // reads prev-layer bits tile 0
    scan_tile(9, 1, m);                // finish PREV layer's last tile (prev m)
    __syncthreads();
    m = 0.0f;
    for (int mt = 0; mt < NMT; ++mt) {
      f32x4 c0 = {bc0, bc0, bc0, bc0};
      f32x4 c1 = {bc1, bc1, bc1, bc1};
      const unsigned short* ab = &Atile[(mt & 1) * (16 * AP) + c16 * AP + quad * 8];
      #pragma unroll
      for (int ks = 0; ks < 8; ++ks) {
        s16x8 a = *(const s16x8*)(ab + ks * 32);
        c0 = __builtin_amdgcn_mfma_f32_16x16x32_bf16(a, wf0[ks], c0, 0, 0, 0);
        c1 = __builtin_amdgcn_mfma_f32_16x16x32_bf16(a, wf1[ks], c1, 0, 0, 0);
      }
      store_c(mt & 1, c0, c1);
      if (mt < NMT - 1) expand_tile(mt + 1, (mt + 1) & 1);
      if (mt > 0) scan_tile(mt - 1, (mt - 1) & 1, m);
      __syncthreads();
    }
    // pending: scan(9) on sc[1]
  }

  // ---- output layer: GEMM || mo-scan, then softmax accumulate (t > 50) ----
  {
    s16x8 wo0[8], wo1[8];
    #pragma unroll
    for (int ks = 0; ks < 8; ++ks) {
      s16x8 z = {0, 0, 0, 0, 0, 0, 0, 0};
      wo0[ks] = (col0 < NOUT) ? *(const s16x8*)(wsb + WS_WO + col0 * H + ks * 32 + quad * 8) : z;
      wo1[ks] = (col1 < NOUT) ? *(const s16x8*)(wsb + WS_WO + col1 * H + ks * 32 + quad * 8) : z;
      asm volatile("" : "+v"(wo0[ks]));
      asm volatile("" : "+v"(wo1[ks]));
    }
    expand_tile(0, 0);
    scan_tile(9, 1, m);                // finish L4's last tile
    __syncthreads();

    float mo = 0.0f;
    float a0 = 0.f, a1 = 0.f, a2 = 0.f, a3 = 0.f;

    auto moscan = [&](int mt, int sb) {
      if (tid < 208) {
        f32x4* vp = (f32x4*)&sc[sb * SCB + tid * CST];
        f32x4 v[4];
        #pragma unroll
        for (int j = 0; j < 4; ++j) v[j] = vp[j];
        #pragma unroll
        for (int r = 0; r < 16; ++r) {
          int t = mt * 16 + r;
          if (t < T_N) {
            float reset = (mo > 1.0f) ? 1.0f : 0.0f;
            mo = 0.9f * mo + v[r / 4][r % 4] - reset;
            v[r / 4][r % 4] = mo;
          }
        }
        #pragma unroll
        for (int j = 0; j < 4; ++j) vp[j] = v[j];
      }
    };
    auto softmax_t = [&](int mt, int sb) {
      #pragma unroll
      for (int rr = 0; rr < 2; ++rr) {
        int r = 2 * wave + rr;
        int t = mt * 16 + r;
        if (t > 50 && t < T_N) {        // wave-uniform
          const float* sb_p = &sc[sb * SCB + r];
          float v0 = sb_p[lane * CST];
          float v1 = sb_p[(64 + lane) * CST];
          float v2 = sb_p[(128 + lane) * CST];
          bool has3 = (lane < 8);        // n=192+lane valid only for n<200
          float v3 = has3 ? sb_p[(192 + lane) * CST] : -INFINITY;
          float mx = fmaxf(fmaxf(v0, v1), fmaxf(v2, v3));
          #pragma unroll
          for (int d = 32; d >= 1; d >>= 1) mx = fmaxf(mx, __shfl_xor(mx, d));
          float e0 = __expf(v0 - mx), e1 = __expf(v1 - mx), e2 = __expf(v2 - mx);
          float e3 = has3 ? __expf(v3 - mx) : 0.0f;
          float s = e0 + e1 + e2 + e3;
          #pragma unroll
          for (int d = 32; d >= 1; d >>= 1) s += __shfl_xor(s, d);
          float inv = 1.0f / s;
          a0 += e0 * inv; a1 += e1 * inv; a2 += e2 * inv; a3 += e3 * inv;
        }
      }
    };

    for (int mt = 0; mt < NMT; ++mt) {
      f32x4 c0 = {0.f, 0.f, 0.f, 0.f};
      f32x4 c1 = {0.f, 0.f, 0.f, 0.f};
      const unsigned short* ab = &Atile[(mt & 1) * (16 * AP) + c16 * AP + quad * 8];
      #pragma unroll
      for (int ks = 0; ks < 8; ++ks) {
        s16x8 a = *(const s16x8*)(ab + ks * 32);
        c0 = __builtin_amdgcn_mfma_f32_16x16x32_bf16(a, wo0[ks], c0, 0, 0, 0);
        c1 = __builtin_amdgcn_mfma_f32_16x16x32_bf16(a, wo1[ks], c1, 0, 0, 0);
      }
      store_c(mt & 1, c0, c1);
      if (mt < NMT - 1) expand_tile(mt + 1, (mt + 1) & 1);
      if (mt > 0) moscan(mt - 1, (mt - 1) & 1);
      __syncthreads();
      if (mt > 0) { softmax_t(mt - 1, (mt - 1) & 1); __syncthreads(); }
    }
    moscan(9, 1);  __syncthreads();
    softmax_t(9, 1); __syncthreads();

    // merge 8 per-wave accumulators (sc reused flat), store f32
    sc[wave * 260 + lane]       = a0;
    sc[wave * 260 + 64 + lane]  = a1;
    sc[wave * 260 + 128 + lane] = a2;
    if (lane < 8) sc[wave * 260 + 192 + lane] = a3;
    __syncthreads();
    if (tid < NOUT) {
      float v = 0.f;
      #pragma unroll
      for (int w = 0; w < 8; ++w) v += sc[w * 260 + tid];
      out[(size_t)bidx * NOUT + tid] = v;
    }
  }
}

extern "C" void kernel_launch(void* const* d_in, const int* in_sizes, int n_in,
                              void* d_out, int out_size, void* d_ws, size_t ws_size,
                              hipStream_t stream) {
  (void)in_sizes; (void)n_in; (void)ws_size; (void)out_size;
  unsigned short* wsb = (unsigned short*)d_ws;
  cvt_weights<<<256, 256, 0, stream>>>(
      (const float*)d_in[1], (const float*)d_in[3], (const float*)d_in[5],
      (const float*)d_in[7], (const float*)d_in[9], wsb);
  snn_fused<<<2048, 512, 0, stream>>>(
      (const float*)d_in[0], wsb,
      (const float*)d_in[2], (const float*)d_in[4],
      (const float*)d_in[6], (const float*)d_in[8],
      (float*)d_out);
}

// Round 7
// 403.217 us; speedup vs baseline: 1.7341x; 1.0241x over previous
//
#include <hip/hip_runtime.h>
#include <math.h>

// SNN forward, fused per batch element. Inputs f32, output f32 [2048][200].
// R7: spikes NEVER materialize in LDS as bf16. GEMM A-fragments are expanded
// from the bit-packed spike masks directly in VGPRs (mul-spread trick:
// t*0x8001 puts bit2j at 2j and bit2j+1 at 16+2j; (r2&mask_j)*(0x3F80>>2j)
// builds the packed-bf16 pair). Ballot masks accumulated per-lane and written
// once per tile (16-lane ds_write_b64). 512 thr / 8 waves / 2 blocks/CU.

#define T_N 150
#define DIN 20
#define H 256
#define NOUT 200
#define NMT 10
#define CST 20           // sc col stride (f32): 16 rows + 4 pad, 16B-aligned cols
#define SCB (256 * CST)  // sc buffer stride (5120 f32)
#define XAP 40           // xa row stride (bf16)
#define BW 12            // bits row stride (dwords): 48 B -> 16B-aligned rows

#define WS_W1 0
#define WS_W2 5120
#define WS_W3 70656
#define WS_W4 136192
#define WS_WO 201728
#define WS_TOT 252928

typedef short s16x8 __attribute__((ext_vector_type(8)));
typedef float f32x4 __attribute__((ext_vector_type(4)));
typedef unsigned int u32x4 __attribute__((ext_vector_type(4)));

__device__ __forceinline__ unsigned short f2bf(float f) {
  union { float f; unsigned int i; } v; v.f = f;
  unsigned int r = v.i + 0x7FFFu + ((v.i >> 16) & 1u);
  return (unsigned short)(r >> 16);
}

__global__ void cvt_weights(const float* __restrict__ W1, const float* __restrict__ W2,
                            const float* __restrict__ W3, const float* __restrict__ W4,
                            const float* __restrict__ Wo, unsigned short* __restrict__ ws) {
  int idx = blockIdx.x * blockDim.x + threadIdx.x;
  int stride = gridDim.x * blockDim.x;
  for (int i = idx; i < WS_TOT; i += stride) {
    float v;
    if (i < WS_W2)      v = W1[i - WS_W1];
    else if (i < WS_W3) v = W2[i - WS_W2];
    else if (i < WS_W4) v = W3[i - WS_W3];
    else if (i < WS_WO) v = W4[i - WS_W4];
    else                v = Wo[i - WS_WO];
    ws[i] = f2bf(v);
  }
}

// expand 8 spike bits (byte t) -> packed-bf16 x8 fragment (0.0 / 1.0)
__device__ __forceinline__ s16x8 expand8(unsigned int t) {
  unsigned int r2 = t * 0x8001u;   // bit 2j -> pos 2j ; bit 2j+1 -> pos 16+2j
  u32x4 d;
  d[0] = (r2 & 0x00010001u) * 0x3F80u;
  d[1] = (r2 & 0x00040004u) * 0x0FE0u;
  d[2] = (r2 & 0x00100010u) * 0x03F8u;
  d[3] = (r2 & 0x00400040u) * 0x00FEu;
  union { u32x4 u; s16x8 s; } cv; cv.u = d;
  return cv.s;
}

__global__ __launch_bounds__(512, 4) void snn_fused(
    const float* __restrict__ x,             // [2048][150][20] f32
    const unsigned short* __restrict__ wsb,  // bf16 weights (d_ws)
    const float* __restrict__ b1,            // [256] f32
    const float* __restrict__ b2,
    const float* __restrict__ b3,
    const float* __restrict__ b4,
    float* __restrict__ out)                 // [2048][200] f32
{
  __shared__ float sc[2 * SCB];              // 40960 B, col-major C bounce (dbuf)
  __shared__ unsigned int bits[160 * BW];    // 7680 B, bit-packed spikes (in place)
  __shared__ unsigned short xa[160 * XAP];   // 12800 B, padded bf16 x for layer 1
                                             // total 61440 B

  const int tid  = threadIdx.x;
  const int lane = tid & 63;
  const int wave = tid >> 6;    // 0..7
  const int c16  = lane & 15;   // MFMA: A row m / B col n / C col
  const int quad = lane >> 4;   // MFMA: k-chunk (A/B), row-group (C)
  const int shq  = quad * 8;    // bit shift for this lane's mask byte
  const int bidx = blockIdx.x;
  const int col0 = 2 * wave * 16 + c16;
  const int col1 = col0 + 16;

  // membrane scan of tile mt from sc[sb] (col-major); masks kept per-lane,
  // single 16-lane ds_write_b64 at the end.
  auto scan_tile = [&](int mt, int sb, float& m) {
    if (tid < 256) {
      const f32x4* vp = (const f32x4*)&sc[sb * SCB + tid * CST];
      f32x4 v[4];
      #pragma unroll
      for (int j = 0; j < 4; ++j) v[j] = vp[j];
      unsigned long long keep = 0ull;
      #pragma unroll
      for (int r = 0; r < 16; ++r) {
        int t = mt * 16 + r;
        if (t < T_N) {
          float inp = v[r / 4][r % 4];     // bias folded into GEMM C-init
          float reset = (m > 1.0f) ? 1.0f : 0.0f;
          m = 0.9f * m + inp - reset;
          unsigned long long msk = __ballot(m > 1.0f);
          if (lane == r) keep = msk;
        }
      }
      if (lane < 16)
        *(unsigned long long*)&bits[(mt * 16 + lane) * BW + wave * 2] = keep;
    }
  };

  auto store_c = [&](int sb, f32x4 c0, f32x4 c1) {
    *(f32x4*)&sc[sb * SCB + col0 * CST + quad * 4] = c0;
    *(f32x4*)&sc[sb * SCB + col1 * CST + quad * 4] = c1;
  };

  // ---- init: zero xa (pads must be 0) and bits (rows 150-159 stay 0) ----
  for (int i = tid; i < (160 * XAP) / 2; i += 512) ((unsigned int*)xa)[i] = 0;
  for (int i = tid; i < 160 * BW; i += 512) bits[i] = 0;
  __syncthreads();
  const float* xb = x + (size_t)bidx * (T_N * DIN);
  for (int e = tid; e < T_N * DIN; e += 512) {
    int t = e / DIN;
    int i = e - t * DIN;
    xa[t * XAP + i] = f2bf(xb[e]);
  }

  float m = 0.0f;

  // ---- layer 1: x @ W1^T (K=20 pad 32), pipelined GEMM || scan ----
  {
    s16x8 w1f[2];
    #pragma unroll
    for (int i = 0; i < 2; ++i) {
      int n = (i == 0) ? col0 : col1;
      #pragma unroll
      for (int j = 0; j < 8; ++j) {
        int k = shq + j;
        w1f[i][j] = (k < DIN) ? (short)wsb[WS_W1 + n * DIN + k] : (short)0;
      }
      asm volatile("" : "+v"(w1f[i]));
    }
    float bc0 = b1[col0], bc1 = b1[col1];
    __syncthreads();  // xa staged
    for (int mt = 0; mt < NMT; ++mt) {
      const s16x8 a1 = *(const s16x8*)&xa[(mt * 16 + c16) * XAP + shq];
      f32x4 c0 = {bc0, bc0, bc0, bc0};
      f32x4 c1 = {bc1, bc1, bc1, bc1};
      c0 = __builtin_amdgcn_mfma_f32_16x16x32_bf16(a1, w1f[0], c0, 0, 0, 0);
      c1 = __builtin_amdgcn_mfma_f32_16x16x32_bf16(a1, w1f[1], c1, 0, 0, 0);
      store_c(mt & 1, c0, c1);
      if (mt > 0) scan_tile(mt - 1, (mt - 1) & 1, m);
      __syncthreads();
    }
    // pending: scan(9) on sc[1] -> next layer's prologue
  }

  // ---- layers 2..4: GEMM straight from bit-masks, 1 barrier/tile ----
  const float* bsl[3] = {b2, b3, b4};
  const int wofs[3] = {WS_W2, WS_W3, WS_W4};
  for (int l = 0; l < 3; ++l) {
    const unsigned short* wl = wsb + wofs[l];
    s16x8 wf0[8], wf1[8];
    #pragma unroll
    for (int ks = 0; ks < 8; ++ks) {
      wf0[ks] = *(const s16x8*)(wl + col0 * H + ks * 32 + shq);
      wf1[ks] = *(const s16x8*)(wl + col1 * H + ks * 32 + shq);
      asm volatile("" : "+v"(wf0[ks]));
      asm volatile("" : "+v"(wf1[ks]));
    }
    float bc0 = bsl[l][col0], bc1 = bsl[l][col1];
    scan_tile(9, 1, m);                // finish PREV layer's last tile (prev m)
    __syncthreads();
    m = 0.0f;
    for (int mt = 0; mt < NMT; ++mt) {
      // load this lane's row-mask (row = mt*16+c16, 32B = dwords 0-7)
      const unsigned int* bp = &bits[(mt * 16 + c16) * BW];
      u32x4 rm0 = *(const u32x4*)bp;
      u32x4 rm1 = *(const u32x4*)(bp + 4);
      unsigned int rm[8] = {rm0[0], rm0[1], rm0[2], rm0[3],
                            rm1[0], rm1[1], rm1[2], rm1[3]};
      f32x4 c0 = {bc0, bc0, bc0, bc0};
      f32x4 c1 = {bc1, bc1, bc1, bc1};
      #pragma unroll
      for (int ks = 0; ks < 8; ++ks) {
        s16x8 a = expand8((rm[ks] >> shq) & 0xFFu);
        c0 = __builtin_amdgcn_mfma_f32_16x16x32_bf16(a, wf0[ks], c0, 0, 0, 0);
        c1 = __builtin_amdgcn_mfma_f32_16x16x32_bf16(a, wf1[ks], c1, 0, 0, 0);
      }
      store_c(mt & 1, c0, c1);
      if (mt > 0) scan_tile(mt - 1, (mt - 1) & 1, m);
      __syncthreads();
    }
    // pending: scan(9) on sc[1]
  }

  // ---- output layer: GEMM || mo-scan, then softmax accumulate (t > 50) ----
  {
    s16x8 wo0[8], wo1[8];
    #pragma unroll
    for (int ks = 0; ks < 8; ++ks) {
      s16x8 z = {0, 0, 0, 0, 0, 0, 0, 0};
      wo0[ks] = (col0 < NOUT) ? *(const s16x8*)(wsb + WS_WO + col0 * H + ks * 32 + shq) : z;
      wo1[ks] = (col1 < NOUT) ? *(const s16x8*)(wsb + WS_WO + col1 * H + ks * 32 + shq) : z;
      asm volatile("" : "+v"(wo0[ks]));
      asm volatile("" : "+v"(wo1[ks]));
    }
    scan_tile(9, 1, m);                // finish L4's last tile
    __syncthreads();

    float mo = 0.0f;
    float a0 = 0.f, a1 = 0.f, a2 = 0.f, a3 = 0.f;

    auto moscan = [&](int mt, int sb) {
      if (tid < 208) {
        f32x4* vp = (f32x4*)&sc[sb * SCB + tid * CST];
        f32x4 v[4];
        #pragma unroll
        for (int j = 0; j < 4; ++j) v[j] = vp[j];
        #pragma unroll
        for (int r = 0; r < 16; ++r) {
          int t = mt * 16 + r;
          if (t < T_N) {
            float reset = (mo > 1.0f) ? 1.0f : 0.0f;
            mo = 0.9f * mo + v[r / 4][r % 4] - reset;
            v[r / 4][r % 4] = mo;
          }
        }
        #pragma unroll
        for (int j = 0; j < 4; ++j) vp[j] = v[j];
      }
    };
    auto softmax_t = [&](int mt, int sb) {
      #pragma unroll
      for (int rr = 0; rr < 2; ++rr) {
        int r = 2 * wave + rr;
        int t = mt * 16 + r;
        if (t > 50 && t < T_N) {        // wave-uniform
          const float* sb_p = &sc[sb * SCB + r];
          float v0 = sb_p[lane * CST];
          float v1 = sb_p[(64 + lane) * CST];
          float v2 = sb_p[(128 + lane) * CST];
          bool has3 = (lane < 8);        // n=192+lane valid only for n<200
          float v3 = has3 ? sb_p[(192 + lane) * CST] : -INFINITY;
          float mx = fmaxf(fmaxf(v0, v1), fmaxf(v2, v3));
          #pragma unroll
          for (int d = 32; d >= 1; d >>= 1) mx = fmaxf(mx, __shfl_xor(mx, d));
          float e0 = __expf(v0 - mx), e1 = __expf(v1 - mx), e2 = __expf(v2 - mx);
          float e3 = has3 ? __expf(v3 - mx) : 0.0f;
          float s = e0 + e1 + e2 + e3;
          #pragma unroll
          for (int d = 32; d >= 1; d >>= 1) s += __shfl_xor(s, d);
          float inv = 1.0f / s;
          a0 += e0 * inv; a1 += e1 * inv; a2 += e2 * inv; a3 += e3 * inv;
        }
      }
    };

    for (int mt = 0; mt < NMT; ++mt) {
      const unsigned int* bp = &bits[(mt * 16 + c16) * BW];
      u32x4 rm0 = *(const u32x4*)bp;
      u32x4 rm1 = *(const u32x4*)(bp + 4);
      unsigned int rm[8] = {rm0[0], rm0[1], rm0[2], rm0[3],
                            rm1[0], rm1[1], rm1[2], rm1[3]};
      f32x4 c0 = {0.f, 0.f, 0.f, 0.f};
      f32x4 c1 = {0.f, 0.f, 0.f, 0.f};
      #pragma unroll
      for (int ks = 0; ks < 8; ++ks) {
        s16x8 a = expand8((rm[ks] >> shq) & 0xFFu);
        c0 = __builtin_amdgcn_mfma_f32_16x16x32_bf16(a, wo0[ks], c0, 0, 0, 0);
        c1 = __builtin_amdgcn_mfma_f32_16x16x32_bf16(a, wo1[ks], c1, 0, 0, 0);
      }
      store_c(mt & 1, c0, c1);
      if (mt > 0) moscan(mt - 1, (mt - 1) & 1);
      __syncthreads();
      if (mt > 0) { softmax_t(mt - 1, (mt - 1) & 1); __syncthreads(); }
    }
    moscan(9, 1);  __syncthreads();
    softmax_t(9, 1); __syncthreads();

    // merge 8 per-wave accumulators (sc reused flat), store f32
    sc[wave * 260 + lane]       = a0;
    sc[wave * 260 + 64 + lane]  = a1;
    sc[wave * 260 + 128 + lane] = a2;
    if (lane < 8) sc[wave * 260 + 192 + lane] = a3;
    __syncthreads();
    if (tid < NOUT) {
      float v = 0.f;
      #pragma unroll
      for (int w = 0; w < 8; ++w) v += sc[w * 260 + tid];
      out[(size_t)bidx * NOUT + tid] = v;
    }
  }
}

extern "C" void kernel_launch(void* const* d_in, const int* in_sizes, int n_in,
                              void* d_out, int out_size, void* d_ws, size_t ws_size,
                              hipStream_t stream) {
  (void)in_sizes; (void)n_in; (void)ws_size; (void)out_size;
  unsigned short* wsb = (unsigned short*)d_ws;
  cvt_weights<<<256, 256, 0, stream>>>(
      (const float*)d_in[1], (const float*)d_in[3], (const float*)d_in[5],
      (const float*)d_in[7], (const float*)d_in[9], wsb);
  snn_fused<<<2048, 512, 0, stream>>>(
      (const float*)d_in[0], wsb,
      (const float*)d_in[2], (const float*)d_in[4],
      (const float*)d_in[6], (const float*)d_in[8],
      (float*)d_out);
}